// Round 4
// baseline (271.028 us; speedup 1.0000x reference)
//
#include <hip/hip_runtime.h>
#include <hip/hip_bf16.h>
#include <stdint.h>

// ---- problem constants ----
#define BATCH 4
#define SEQ   8400
#define DM    512
#define KP    8484      // SEQ + 2*42 (edge pad)
#define NWIN  100
#define STEP_ 84
#define PAD_  42
#define NKEY  126
#define MROWS 33600     // BATCH*SEQ

typedef __attribute__((ext_vector_type(8))) short short8;
typedef __attribute__((ext_vector_type(4))) float float4v;
typedef __attribute__((ext_vector_type(4))) unsigned short ushort4v;

#define MFMA16 __builtin_amdgcn_mfma_f32_16x16x32_bf16

__device__ __forceinline__ unsigned short f2bf(float f) {
    union { float f; unsigned u; } v; v.f = f;
    return (unsigned short)((v.u + 0x7FFFu + ((v.u >> 16) & 1u)) >> 16);  // RNE
}
__device__ __forceinline__ unsigned short bfc(float f) {
    __hip_bfloat16 h = __float2bfloat16(f);
    union { __hip_bfloat16 h; unsigned short u; } v; v.h = h;
    return v.u;
}

typedef __attribute__((address_space(1))) const unsigned int as1_cu32;
typedef __attribute__((address_space(3))) unsigned int as3_u32;
__device__ __forceinline__ void gload16(const void* g, void* l) {
    __builtin_amdgcn_global_load_lds((as1_cu32*)g, (as3_u32*)l, 16, 0, 0);
}

// ============ prepass: W (f32 [k][n] 512x512) -> Wt (bf16 [n][k]) ============
__global__ __launch_bounds__(256) void kprep(const float* __restrict__ Wq,
                                             const float* __restrict__ Wk,
                                             const float* __restrict__ Wv,
                                             const float* __restrict__ Wo,
                                             unsigned short* __restrict__ Wt) {
    const float* src = blockIdx.z == 0 ? Wq : blockIdx.z == 1 ? Wk
                     : blockIdx.z == 2 ? Wv : Wo;
    unsigned short* dst = Wt + (size_t)blockIdx.z * DM * DM;
    __shared__ float t[64][65];
    int c = threadIdx.x & 63, r4 = threadIdx.x >> 6;
    int kb = blockIdx.x * 64, nb = blockIdx.y * 64;
    for (int i = 0; i < 16; i++) {
        int r = r4 * 16 + i;
        t[r][c] = src[(size_t)(kb + r) * DM + nb + c];
    }
    __syncthreads();
    for (int i = 0; i < 16; i++) {
        int r = r4 * 16 + i;
        dst[(size_t)(nb + r) * DM + kb + c] = f2bf(t[c][r]);
    }
}

// ============ kernel 1: fused pad+cvt+QKV projection, pipelined ==============
// BM=64, BN=512, BK=32, double-buffered, counted vmcnt (T3-minimum).
// Q/K out: [h*B+b][p][64]; V out transposed: VT[h*B+b][d][p].
__global__ __launch_bounds__(256, 2) void kproj(const float* __restrict__ q,
                                                const float* __restrict__ k,
                                                const float* __restrict__ v,
                                                const unsigned short* __restrict__ Wt,
                                                const float* __restrict__ bq,
                                                const float* __restrict__ bk,
                                                const float* __restrict__ bv,
                                                unsigned short* __restrict__ Qb,
                                                unsigned short* __restrict__ Kb,
                                                unsigned short* __restrict__ VT) {
    int mt = blockIdx.x, z = blockIdx.y;
    int ten = z >> 2, b = z & 3;
    const float* A = (ten == 0 ? q : ten == 1 ? k : v) + (size_t)b * SEQ * DM;
    const unsigned short* W = Wt + (size_t)ten * DM * DM;
    const float* bias = ten == 0 ? bq : ten == 1 ? bk : bv;
    float scale = ten == 0 ? 0.07715167498104595f : 1.f;   // 1/sqrt(168)
    int m0 = mt * 64;

    // A0 [0,8K) A1 [8K,16K) f32 [64][32]; B0 [16K,48K) B1 [48K,80K) bf16 [512][32]
    __shared__ __align__(16) char lds[81920];

    int tid = threadIdx.x, lane = tid & 63, wc = tid >> 6;
    int l15 = lane & 15, g = lane >> 4;

    float4v acc[4][8];
#pragma unroll
    for (int i = 0; i < 4; i++)
#pragma unroll
        for (int j = 0; j < 8; j++) { float4v zz = {0.f,0.f,0.f,0.f}; acc[i][j] = zz; }

    // stage A: 64 rows x 8 f32-chunks, swizzle pos^(r&7); 2 issues/thread
    auto stageA = [&](int kt, int buf) {
#pragma unroll
        for (int it = 0; it < 2; it++) {
            int c = it * 256 + tid;
            int r = c >> 3;
            int pos = (c & 7) ^ (r & 7);
            int p = m0 + r; if (p > KP - 1) p = KP - 1;
            int row = p - PAD_; row = row < 0 ? 0 : (row > SEQ - 1 ? SEQ - 1 : row);
            gload16(A + (size_t)row * DM + kt * 32 + pos * 4,
                    lds + buf * 8192 + (it * 256 + wc * 64) * 16);
        }
    };
    // stage B: 512 rows x 4 bf16-chunks, swizzle pos^((r>>1)&3); 8 issues/thread
    auto stageB = [&](int kt, int buf) {
#pragma unroll
        for (int it = 0; it < 8; it++) {
            int c = it * 256 + tid;
            int r = c >> 2;
            int pos = (c & 3) ^ ((r >> 1) & 3);
            gload16(W + (size_t)r * DM + kt * 32 + pos * 8,
                    lds + 16384 + buf * 32768 + (it * 256 + wc * 64) * 16);
        }
    };

    stageA(0, 0); stageB(0, 0);
#pragma unroll
    for (int t = 0; t < 16; ++t) {
        int cur = t & 1;
        if (t < 15) { stageA(t + 1, cur ^ 1); stageB(t + 1, cur ^ 1); }
        if (t < 15) asm volatile("s_waitcnt vmcnt(10)" ::: "memory");
        else        asm volatile("s_waitcnt vmcnt(0)" ::: "memory");
        __builtin_amdgcn_s_barrier();
        __builtin_amdgcn_sched_barrier(0);
        const char* Ab_ = lds + cur * 8192;
        const char* Bb_ = lds + 16384 + cur * 32768;
        short8 af[4];
#pragma unroll
        for (int i = 0; i < 4; i++) {
            int ra = i * 16 + l15;
            float4v f0 = *(const float4v*)(Ab_ + ra * 128 + (((2 * g) ^ (ra & 7)) << 4));
            float4v f1 = *(const float4v*)(Ab_ + ra * 128 + (((2 * g + 1) ^ (ra & 7)) << 4));
            short8 hv;
            hv[0] = (short)bfc(f0.x); hv[1] = (short)bfc(f0.y);
            hv[2] = (short)bfc(f0.z); hv[3] = (short)bfc(f0.w);
            hv[4] = (short)bfc(f1.x); hv[5] = (short)bfc(f1.y);
            hv[6] = (short)bfc(f1.z); hv[7] = (short)bfc(f1.w);
            af[i] = hv;
        }
        short8 bfr[8];
#pragma unroll
        for (int j = 0; j < 8; j++) {
            int rb = wc * 128 + j * 16 + l15;
            bfr[j] = *(const short8*)(Bb_ + rb * 64 + ((g ^ ((rb >> 1) & 3)) << 4));
        }
#pragma unroll
        for (int i = 0; i < 4; i++)
#pragma unroll
            for (int j = 0; j < 8; j++)
                acc[i][j] = MFMA16(af[i], bfr[j], acc[i][j], 0, 0, 0);
        __builtin_amdgcn_s_barrier();
    }

    if (ten <= 1) {
        // bounce [64][520] u16 then coalesced short8 head-split writes
        unsigned short* Ol = (unsigned short*)lds;
#pragma unroll
        for (int j = 0; j < 8; j++) {
            int n = wc * 128 + j * 16 + l15;
            float bval = bias[n];
#pragma unroll
            for (int i = 0; i < 4; i++) {
                float4v vv = acc[i][j];
#pragma unroll
                for (int r = 0; r < 4; r++)
                    Ol[(i * 16 + g * 4 + r) * 520 + n] = f2bf((vv[r] + bval) * scale);
            }
        }
        __syncthreads();
        unsigned short* O = ten == 0 ? Qb : Kb;
        for (int c = tid; c < 4096; c += 256) {        // 64 rows x 64 chunks
            int row = c >> 6, n8 = c & 63;
            int p = m0 + row;
            if (p < KP) {
                int h = n8 >> 3, ch = n8 & 7;
                *(short8*)(O + ((size_t)(h * BATCH + b) * KP + p) * 64 + ch * 8) =
                    *(const short8*)(Ol + row * 520 + n8 * 8);
            }
        }
    } else {
        // V: direct transposed stores VT[hb][d][p] (lane has 4 consecutive p)
#pragma unroll
        for (int j = 0; j < 8; j++) {
            int n = wc * 128 + j * 16 + l15;
            float bval = bias[n];
            int h = n >> 6, d = n & 63;
            unsigned short* base = VT + ((size_t)(h * BATCH + b) * 64 + d) * KP;
#pragma unroll
            for (int i = 0; i < 4; i++) {
                int p = m0 + i * 16 + g * 4;
                if (p <= KP - 4) {
                    float4v vv = acc[i][j];
                    ushort4v wv;
                    wv[0] = f2bf(vv.x + bval); wv[1] = f2bf(vv.y + bval);
                    wv[2] = f2bf(vv.z + bval); wv[3] = f2bf(vv.w + bval);
                    *(ushort4v*)(base + p) = wv;
                }
            }
        }
    }
}

// ============ kernel 2: windowed causal attention ============================
__global__ __launch_bounds__(384) void kattn(const unsigned short* __restrict__ Qb,
                                             const unsigned short* __restrict__ Kb,
                                             const unsigned short* __restrict__ VT,
                                             unsigned short* __restrict__ attn) {
    int win = blockIdx.x, hb = blockIdx.y;
    int h = hb >> 2, b = hb & 3;
    const unsigned short* Qg = Qb + (size_t)hb * KP * 64;
    const unsigned short* Kg = Kb + (size_t)hb * KP * 64;
    const unsigned short* Vt = VT + (size_t)hb * 64 * KP;
    int p0 = win * STEP_;

    // Ql [0,12288) 96x64; Kl [12288,28672) 128x64; Vl [28672,45056) 64x128;
    // Pl [45056,69632) 96x128. Ol reuses Ql.
    __shared__ __align__(16) char lds[69632];

    int tid = threadIdx.x, lane = tid & 63, f = tid >> 6;
    int l15 = lane & 15, g = lane >> 4;

#pragma unroll
    for (int it = 0; it < 5; it++) {
        int base = it * 384 + f * 64;
        if (base < 768) {                       // Q chunks
            int c = base + lane;
            int qi = c >> 3, kg = (c & 7) ^ (qi & 7);
            gload16(Qg + (size_t)(p0 + PAD_ + qi) * 64 + kg * 8, lds + base * 16);
        } else if (base < 1792) {               // K chunks
            int c = base + lane - 768;
            int x = c >> 3, kg = (c & 7) ^ (x & 7);
            gload16(Kg + (size_t)(p0 + x) * 64 + kg * 8, lds + base * 16);
        }
    }
    for (int c = tid; c < 2048; c += 384) {
        int d = c >> 5, c2 = c & 31;
        ushort4v wv = *(const ushort4v*)(Vt + (size_t)d * KP + p0 + c2 * 4);
        int cx = c2 >> 1;
        *(ushort4v*)(lds + 28672 + d * 256 + (((cx ^ (d & 7)) << 4) | ((c2 & 1) * 8))) = wv;
    }
    __syncthreads();

    short8 bq2[2];
    {
        int r = f * 16 + l15;
#pragma unroll
        for (int ks = 0; ks < 2; ks++) {
            int kg = ks * 4 + g;
            bq2[ks] = *(const short8*)(lds + r * 128 + ((kg ^ (r & 7)) << 4));
        }
    }
    float4v st[8];
#pragma unroll
    for (int xf = 0; xf < 8; xf++) {
        float4v zz = {0.f,0.f,0.f,0.f}; st[xf] = zz;
#pragma unroll
        for (int ks = 0; ks < 2; ks++) {
            int r = xf * 16 + l15;
            int kg = ks * 4 + g;
            short8 a = *(const short8*)(lds + 12288 + r * 128 + ((kg ^ (r & 7)) << 4));
            st[xf] = MFMA16(a, bq2[ks], st[xf], 0, 0, 0);
        }
    }

    int w_abs = PAD_ + f * 16 + l15;
    int w_eff = w_abs > 125 ? 125 : w_abs;
    float mx = -1e30f;
#pragma unroll
    for (int xf = 0; xf < 8; xf++)
#pragma unroll
        for (int r = 0; r < 4; r++) {
            int x = xf * 16 + g * 4 + r;
            float vv = st[xf][r];
            if (x > w_eff) vv = -1e30f;
            st[xf][r] = vv;
            mx = fmaxf(mx, vv);
        }
    mx = fmaxf(mx, __shfl_xor(mx, 16));
    mx = fmaxf(mx, __shfl_xor(mx, 32));
    float s = 0.f;
#pragma unroll
    for (int xf = 0; xf < 8; xf++)
#pragma unroll
        for (int r = 0; r < 4; r++) {
            float e = __expf(st[xf][r] - mx);
            st[xf][r] = e;
            s += e;
        }
    s += __shfl_xor(s, 16);
    s += __shfl_xor(s, 32);
    float inv = 1.f / s;

    {
        int qi = f * 16 + l15;
#pragma unroll
        for (int xf = 0; xf < 8; xf++) {
            ushort4v pw;
#pragma unroll
            for (int r = 0; r < 4; r++) pw[r] = f2bf(st[xf][r] * inv);
            int xc = 2 * xf + (g >> 1);
            *(ushort4v*)(lds + 45056 + qi * 256 + ((xc ^ (qi & 7)) << 4) + (g & 1) * 8) = pw;
        }
    }
    __syncthreads();

    float4v pv[4];
#pragma unroll
    for (int j = 0; j < 4; j++) { float4v zz = {0.f,0.f,0.f,0.f}; pv[j] = zz; }
    int qi = f * 16 + l15;
#pragma unroll
    for (int g2 = 0; g2 < 4; g2++) {
        int xc = g2 * 4 + g;
        short8 a = *(const short8*)(lds + 45056 + qi * 256 + ((xc ^ (qi & 7)) << 4));
#pragma unroll
        for (int j = 0; j < 4; j++) {
            int d = j * 16 + l15;
            short8 bvv = *(const short8*)(lds + 28672 + d * 256 + ((xc ^ (d & 7)) << 4));
            pv[j] = MFMA16(a, bvv, pv[j], 0, 0, 0);
        }
    }

    unsigned short* Ol = (unsigned short*)lds;
#pragma unroll
    for (int j = 0; j < 4; j++) {
        int d = j * 16 + l15;
#pragma unroll
        for (int r = 0; r < 4; r++) {
            int qq = f * 16 + g * 4 + r;
            int byte = qq * 128 + ((((d >> 3) ^ (qq & 7))) << 4) + (d & 7) * 2;
            *(unsigned short*)((char*)Ol + byte) = f2bf(pv[j][r]);
        }
    }
    __syncthreads();
    for (int c = tid; c < 672; c += 384) {
        int qq = c >> 3, ch = c & 7;
        short8 hv = *(const short8*)((char*)Ol + qq * 128 + ((ch ^ (qq & 7)) << 4));
        size_t off = ((size_t)(b * SEQ + win * STEP_ + qq) * DM) + h * 64 + ch * 8;
        *(short8*)(attn + off) = hv;
    }
}

// ============ kernel 3: output projection, pipelined BM=64/BN=512/BK=32 ======
__global__ __launch_bounds__(256, 2) void kout(const unsigned short* __restrict__ Ab,
                                               const unsigned short* __restrict__ W,
                                               const float* __restrict__ bias,
                                               float* __restrict__ Out) {
    int m0 = blockIdx.x * 64;
    // A0 [0,4K) A1 [4K,8K) bf16 [64][32]; B0 [8K,40K) B1 [40K,72K) bf16 [512][32]
    __shared__ __align__(16) char lds[73728];
    int tid = threadIdx.x, lane = tid & 63, wc = tid >> 6;
    int l15 = lane & 15, g = lane >> 4;

    float4v acc[4][8];
#pragma unroll
    for (int i = 0; i < 4; i++)
#pragma unroll
        for (int j = 0; j < 8; j++) { float4v zz = {0.f,0.f,0.f,0.f}; acc[i][j] = zz; }

    auto stageA = [&](int kt, int buf) {
        int c = tid;                               // 256 chunks, 1 issue/thread
        int r = c >> 2;
        int pos = (c & 3) ^ ((r >> 1) & 3);
        int row = m0 + r; if (row > MROWS - 1) row = MROWS - 1;
        gload16(Ab + (size_t)row * DM + kt * 32 + pos * 8,
                lds + buf * 4096 + (wc * 64) * 16);
    };
    auto stageB = [&](int kt, int buf) {
#pragma unroll
        for (int it = 0; it < 8; it++) {
            int c = it * 256 + tid;
            int r = c >> 2;
            int pos = (c & 3) ^ ((r >> 1) & 3);
            gload16(W + (size_t)r * DM + kt * 32 + pos * 8,
                    lds + 8192 + buf * 32768 + (it * 256 + wc * 64) * 16);
        }
    };

    stageA(0, 0); stageB(0, 0);
#pragma unroll
    for (int t = 0; t < 16; ++t) {
        int cur = t & 1;
        if (t < 15) { stageA(t + 1, cur ^ 1); stageB(t + 1, cur ^ 1); }
        if (t < 15) asm volatile("s_waitcnt vmcnt(9)" ::: "memory");
        else        asm volatile("s_waitcnt vmcnt(0)" ::: "memory");
        __builtin_amdgcn_s_barrier();
        __builtin_amdgcn_sched_barrier(0);
        const char* Ab_ = lds + cur * 4096;
        const char* Bb_ = lds + 8192 + cur * 32768;
        short8 af[4];
#pragma unroll
        for (int i = 0; i < 4; i++) {
            int ra = i * 16 + l15;
            af[i] = *(const short8*)(Ab_ + ra * 64 + ((g ^ ((ra >> 1) & 3)) << 4));
        }
        short8 bfr[8];
#pragma unroll
        for (int j = 0; j < 8; j++) {
            int rb = wc * 128 + j * 16 + l15;
            bfr[j] = *(const short8*)(Bb_ + rb * 64 + ((g ^ ((rb >> 1) & 3)) << 4));
        }
#pragma unroll
        for (int i = 0; i < 4; i++)
#pragma unroll
            for (int j = 0; j < 8; j++)
                acc[i][j] = MFMA16(af[i], bfr[j], acc[i][j], 0, 0, 0);
        __builtin_amdgcn_s_barrier();
    }
#pragma unroll
    for (int j = 0; j < 8; j++) {
        int n = wc * 128 + j * 16 + l15;
        float bv = bias[n];
#pragma unroll
        for (int i = 0; i < 4; i++) {
            float4v vv = acc[i][j];
#pragma unroll
            for (int r = 0; r < 4; r++) {
                int m = m0 + i * 16 + g * 4 + r;
                if (m < MROWS) Out[(size_t)m * DM + n] = vv[r] + bv;
            }
        }
    }
}

// ============ launch =========================================================
extern "C" void kernel_launch(void* const* d_in, const int* in_sizes, int n_in,
                              void* d_out, int out_size, void* d_ws, size_t ws_size,
                              hipStream_t stream) {
    const float* q  = (const float*)d_in[0];
    const float* k  = (const float*)d_in[1];
    const float* v  = (const float*)d_in[2];
    const float* Wq = (const float*)d_in[3];
    const float* bq = (const float*)d_in[4];
    const float* Wk = (const float*)d_in[5];
    const float* bk = (const float*)d_in[6];
    const float* Wv = (const float*)d_in[7];
    const float* bv = (const float*)d_in[8];
    const float* Wo = (const float*)d_in[9];
    const float* bo = (const float*)d_in[10];

    const size_t WT_ELEMS  = (size_t)4 * DM * DM;
    const size_t QKV_ELEMS = (size_t)32 * KP * 64;
    const size_t ATT_ELEMS = (size_t)MROWS * DM;
    size_t need = (WT_ELEMS + 3 * QKV_ELEMS + ATT_ELEMS) * 2;
    if (ws_size < need) return;

    unsigned short* Wt = (unsigned short*)d_ws;
    unsigned short* Qb = Wt + WT_ELEMS;
    unsigned short* Kb = Qb + QKV_ELEMS;
    unsigned short* VT = Kb + QKV_ELEMS;
    unsigned short* Ab = VT + QKV_ELEMS;

    kprep<<<dim3(8, 8, 4), dim3(256), 0, stream>>>(Wq, Wk, Wv, Wo, Wt);
    kproj<<<dim3(133, 12), dim3(256), 0, stream>>>(q, k, v, Wt, bq, bk, bv,
                                                   Qb, Kb, VT);
    kattn<<<dim3(NWIN, 32), dim3(384), 0, stream>>>(Qb, Kb, VT, Ab);
    kout<<<dim3(525), dim3(256), 0, stream>>>(Ab, Wt + 3 * DM * DM, bo,
                                              (float*)d_out);
}